// Round 1
// baseline (1082.981 us; speedup 1.0000x reference)
//
#include <hip/hip_runtime.h>
#include <math.h>

// GCN: h0 = lrelu(Agg(x@W0)+b0); h1 = lrelu(Agg(h0@W1)+b1); out = sigmoid(h1[idx]@Wm+bm)
// Agg uses symmetric norm with self loops: agg[d] = sum_e dinv[s]*dinv[d]*h[s] + dinv[i]^2*h[i]
// We pre-scale h by dinv[row] in GEMM epilogues so edges only need dinv[dst].

__device__ __forceinline__ float lrelu(float x) { return x > 0.0f ? x : 0.01f * x; }

__global__ void k_deg(const int* __restrict__ dst, int E, float* __restrict__ deg) {
    int i = blockIdx.x * blockDim.x + threadIdx.x;
    if (i < E) atomicAdd(deg + dst[i], 1.0f);
}

__global__ void k_dinv(float* __restrict__ deg, int N) {
    int i = blockIdx.x * blockDim.x + threadIdx.x;
    if (i < N) deg[i] = rsqrtf(deg[i] + 1.0f);  // +1 for self loop
}

// h_s = (x @ W0) * dinv[row]  -> hout;   agg init = h_s * dinv[row] -> agg
// x: [N,128], W0: [128,64]. Wave-per-row; W column in VGPRs (two K-halves of 64).
__global__ __launch_bounds__(256) void k_gemm1(const float* __restrict__ x,
                                               const float* __restrict__ W0,
                                               const float* __restrict__ dinv,
                                               float* __restrict__ hout,
                                               float* __restrict__ agg, int N) {
    int tid = threadIdx.x, lane = tid & 63, wv = tid >> 6;
    const int R = 8;
    int row0 = (blockIdx.x * 4 + wv) * R;
    float acc[R];
#pragma unroll
    for (int r = 0; r < R; ++r) acc[r] = 0.0f;

#pragma unroll
    for (int h = 0; h < 2; ++h) {
        float wreg[64];
#pragma unroll
        for (int k = 0; k < 64; ++k) wreg[k] = W0[(h * 64 + k) * 64 + lane];
#pragma unroll
        for (int r = 0; r < R; ++r) {
            int row = row0 + r;
            if (row >= N) break;
            float xv = x[(size_t)row * 128 + h * 64 + lane];
#pragma unroll
            for (int k = 0; k < 64; ++k)
                acc[r] = fmaf(__shfl(xv, k), wreg[k], acc[r]);
        }
    }
#pragma unroll
    for (int r = 0; r < R; ++r) {
        int row = row0 + r;
        if (row >= N) return;
        float dv = dinv[row];
        float hs = acc[r] * dv;
        hout[(size_t)row * 64 + lane] = hs;
        agg[(size_t)row * 64 + lane] = hs * dv;  // self-loop init: dinv^2 * h
    }
}

// a = lrelu(agg0 + b0); h_s = (a @ W1) * dinv -> hout; agg (in place) = h_s * dinv
// Safe in-place: each wave reads its full row into registers before overwriting.
__global__ __launch_bounds__(256) void k_gemm2(const float* __restrict__ b0,
                                               const float* __restrict__ W1,
                                               const float* __restrict__ dinv,
                                               float* __restrict__ hout,
                                               float* __restrict__ agg, int N) {
    int tid = threadIdx.x, lane = tid & 63, wv = tid >> 6;
    float wreg[64];
#pragma unroll
    for (int k = 0; k < 64; ++k) wreg[k] = W1[k * 64 + lane];
    float bias = b0[lane];
    const int R = 8;
    int row0 = (blockIdx.x * 4 + wv) * R;
#pragma unroll
    for (int r = 0; r < R; ++r) {
        int row = row0 + r;
        if (row >= N) return;
        float a = lrelu(agg[(size_t)row * 64 + lane] + bias);
        float acc = 0.0f;
#pragma unroll
        for (int k = 0; k < 64; ++k)
            acc = fmaf(__shfl(a, k), wreg[k], acc);
        float dv = dinv[row];
        float hs = acc * dv;
        hout[(size_t)row * 64 + lane] = hs;
        agg[(size_t)row * 64 + lane] = hs * dv;
    }
}

// agg[dst] += h_s[src] * dinv[dst]   (h_s already carries dinv[src])
// One wave per edge (grid-stride); lane = channel; coalesced 256B atomic row add.
__global__ void k_edge(const int* __restrict__ src, const int* __restrict__ dst,
                       const float* __restrict__ dinv, const float* __restrict__ h,
                       float* __restrict__ agg, int E) {
    int lane = threadIdx.x & 63;
    int wv = (blockIdx.x * blockDim.x + threadIdx.x) >> 6;
    int nw = (gridDim.x * blockDim.x) >> 6;
    for (int e = wv; e < E; e += nw) {
        int s = src[e], d = dst[e];
        float v = h[(size_t)s * 64 + lane] * dinv[d];
        atomicAdd(agg + (size_t)d * 64 + lane, v);
    }
}

// h_sel = lrelu(agg1[idx]+b1) -> out[0:NSEL*64]; sigmoid(h_sel@Wm+bm) -> out[NSEL*64:]
__global__ void k_out(const int* __restrict__ idx, const float* __restrict__ agg,
                      const float* __restrict__ b1, const float* __restrict__ Wm,
                      const float* __restrict__ bm, float* __restrict__ out, int NSEL) {
    int lane = threadIdx.x & 63;
    int wv = (blockIdx.x * blockDim.x + threadIdx.x) >> 6;
    if (wv >= NSEL) return;
    int node = idx[wv];
    float hs = lrelu(agg[(size_t)node * 64 + lane] + b1[lane]);
    out[(size_t)wv * 64 + lane] = hs;
#pragma unroll
    for (int o = 0; o < 5; ++o) {
        float p = hs * Wm[lane * 5 + o];
#pragma unroll
        for (int off = 32; off > 0; off >>= 1) p += __shfl_down(p, off);
        if (lane == 0)
            out[(size_t)NSEL * 64 + (size_t)wv * 5 + o] =
                1.0f / (1.0f + expf(-(p + bm[o])));
    }
}

extern "C" void kernel_launch(void* const* d_in, const int* in_sizes, int n_in,
                              void* d_out, int out_size, void* d_ws, size_t ws_size,
                              hipStream_t stream) {
    const float* x   = (const float*)d_in[0];
    const int*   ei  = (const int*)d_in[1];
    const int*   idx = (const int*)d_in[2];
    const float* W0  = (const float*)d_in[3];
    const float* b0  = (const float*)d_in[4];
    const float* W1  = (const float*)d_in[5];
    const float* b1  = (const float*)d_in[6];
    const float* Wm  = (const float*)d_in[7];
    const float* bm  = (const float*)d_in[8];

    int N    = in_sizes[0] / 128;
    int E    = in_sizes[1] / 2;
    int NSEL = in_sizes[2];
    const int* src = ei;
    const int* dst = ei + E;

    float* ws   = (float*)d_ws;
    float* deg  = ws;                                  // N floats (deg -> dinv in place)
    size_t o1   = (((size_t)N + 255) & ~(size_t)255);
    float* buf1 = ws + o1;                             // N*64: h_s (layer1), then h_s (layer2)
    float* buf2 = buf1 + (size_t)N * 64;               // N*64: agg0, then agg1 (in place)

    hipMemsetAsync(deg, 0, (size_t)N * sizeof(float), stream);
    k_deg<<<(E + 255) / 256, 256, 0, stream>>>(dst, E, deg);
    k_dinv<<<(N + 255) / 256, 256, 0, stream>>>(deg, N);

    int gemm_blocks = (N + 31) / 32;  // 4 waves/block * 8 rows/wave
    k_gemm1<<<gemm_blocks, 256, 0, stream>>>(x, W0, deg, buf1, buf2, N);
    k_edge<<<32768, 256, 0, stream>>>(src, dst, deg, buf1, buf2, E);
    k_gemm2<<<gemm_blocks, 256, 0, stream>>>(b0, W1, deg, buf1, buf2, N);
    k_edge<<<32768, 256, 0, stream>>>(src, dst, deg, buf1, buf2, E);
    k_out<<<(NSEL + 3) / 4, 256, 0, stream>>>(idx, buf2, b1, Wm, bm, (float*)d_out, NSEL);
}

// Round 2
// 650.200 us; speedup vs baseline: 1.6656x; 1.6656x over previous
//
#include <hip/hip_runtime.h>
#include <math.h>

// GCN: h0 = lrelu(Agg(x@W0)+b0); h1 = lrelu(Agg(h0@W1)+b1); out = sigmoid(h1[idx]@Wm+bm)
// Agg (sym-norm + self loops): agg[d] = dinv[d] * ( sum_{e:dst=d} h_s[src] + h_s[d] ),
// with h_s = h * dinv[row] (pre-scaled in GEMM epilogue).
// Edges are counting-sorted by dst into CSR once per call -> atomic-free aggregation.

__device__ __forceinline__ float lrelu(float x) { return x > 0.0f ? x : 0.01f * x; }

// ---------- degree / CSR build ----------

__global__ void k_hist(const int* __restrict__ dst, int E, int* __restrict__ cnt) {
    int i = blockIdx.x * blockDim.x + threadIdx.x;
    if (i < E) atomicAdd(cnt + dst[i], 1);
}

__global__ void k_dinv(const int* __restrict__ cnt, float* __restrict__ dinv, int N) {
    int i = blockIdx.x * blockDim.x + threadIdx.x;
    if (i < N) dinv[i] = rsqrtf((float)cnt[i] + 1.0f);  // +1 self loop
}

// 1024 elements per block (256 thr x 4)
__global__ void k_blocksum(const int* __restrict__ cnt, int N, int* __restrict__ bsum) {
    __shared__ int sm[256];
    int b = blockIdx.x, t = threadIdx.x;
    int base = b * 1024 + t * 4;
    int s = 0;
#pragma unroll
    for (int i = 0; i < 4; ++i) { int j = base + i; if (j < N) s += cnt[j]; }
    sm[t] = s; __syncthreads();
    for (int off = 128; off > 0; off >>= 1) {
        if (t < off) sm[t] += sm[t + off];
        __syncthreads();
    }
    if (t == 0) bsum[b] = sm[0];
}

__global__ void k_scan_bsum(int* __restrict__ bsum, int nb, int* __restrict__ offN) {
    if (threadIdx.x == 0 && blockIdx.x == 0) {
        int run = 0;
        for (int i = 0; i < nb; ++i) { int v = bsum[i]; bsum[i] = run; run += v; }
        *offN = run;  // == E
    }
}

__global__ void k_scan_block(const int* __restrict__ cnt, const int* __restrict__ bsum,
                             int* __restrict__ off, int N) {
    __shared__ int sm[256];
    int b = blockIdx.x, t = threadIdx.x;
    int base = b * 1024 + t * 4;
    int v[4];
#pragma unroll
    for (int i = 0; i < 4; ++i) { int j = base + i; v[i] = (j < N) ? cnt[j] : 0; }
    int tsum = v[0] + v[1] + v[2] + v[3];
    sm[t] = tsum; __syncthreads();
    for (int d = 1; d < 256; d <<= 1) {
        int val = (t >= d) ? sm[t - d] : 0;
        __syncthreads();
        sm[t] += val;
        __syncthreads();
    }
    int run = sm[t] - tsum + bsum[b];  // exclusive prefix for this thread
#pragma unroll
    for (int i = 0; i < 4; ++i) {
        int j = base + i;
        if (j < N) off[j] = run;
        run += v[i];
    }
}

__global__ void k_scatter(const int* __restrict__ src, const int* __restrict__ dst,
                          const int* __restrict__ off, int* __restrict__ cnt,
                          int* __restrict__ esorted, int E) {
    int e = blockIdx.x * blockDim.x + threadIdx.x;
    if (e < E) {
        int d = dst[e];
        int p = off[d] + atomicAdd(cnt + d, 1);
        esorted[p] = src[e];
    }
}

// ---------- GEMMs (wave-per-row, W column in VGPRs, row broadcast via shfl) ----------

// h_s = (x @ W0) * dinv[row]  -> hout.   x:[N,128], W0:[128,64]
__global__ __launch_bounds__(256) void k_gemm1(const float* __restrict__ x,
                                               const float* __restrict__ W0,
                                               const float* __restrict__ dinv,
                                               float* __restrict__ hout, int N) {
    int tid = threadIdx.x, lane = tid & 63, wv = tid >> 6;
    const int R = 8;
    int row0 = (blockIdx.x * 4 + wv) * R;
    float acc[R];
#pragma unroll
    for (int r = 0; r < R; ++r) acc[r] = 0.0f;

#pragma unroll
    for (int h = 0; h < 2; ++h) {
        float wreg[64];
#pragma unroll
        for (int k = 0; k < 64; ++k) wreg[k] = W0[(h * 64 + k) * 64 + lane];
#pragma unroll
        for (int r = 0; r < R; ++r) {
            int row = row0 + r;
            if (row >= N) break;
            float xv = x[(size_t)row * 128 + h * 64 + lane];
#pragma unroll
            for (int k = 0; k < 64; ++k)
                acc[r] = fmaf(__shfl(xv, k), wreg[k], acc[r]);
        }
    }
#pragma unroll
    for (int r = 0; r < R; ++r) {
        int row = row0 + r;
        if (row >= N) return;
        hout[(size_t)row * 64 + lane] = acc[r] * dinv[row];
    }
}

// a = lrelu(agg0 + b0); h_s = (a @ W1) * dinv -> hout
__global__ __launch_bounds__(256) void k_gemm2(const float* __restrict__ agg,
                                               const float* __restrict__ b0,
                                               const float* __restrict__ W1,
                                               const float* __restrict__ dinv,
                                               float* __restrict__ hout, int N) {
    int tid = threadIdx.x, lane = tid & 63, wv = tid >> 6;
    float wreg[64];
#pragma unroll
    for (int k = 0; k < 64; ++k) wreg[k] = W1[k * 64 + lane];
    float bias = b0[lane];
    const int R = 8;
    int row0 = (blockIdx.x * 4 + wv) * R;
#pragma unroll
    for (int r = 0; r < R; ++r) {
        int row = row0 + r;
        if (row >= N) return;
        float a = lrelu(agg[(size_t)row * 64 + lane] + bias);
        float acc = 0.0f;
#pragma unroll
        for (int k = 0; k < 64; ++k)
            acc = fmaf(__shfl(a, k), wreg[k], acc);
        hout[(size_t)row * 64 + lane] = acc * dinv[row];
    }
}

// ---------- CSR aggregation: one wave per node, lane = channel ----------

__global__ __launch_bounds__(256) void k_agg(const int* __restrict__ off,
                                             const int* __restrict__ esorted,
                                             const float* __restrict__ dinv,
                                             const float* __restrict__ hs,
                                             float* __restrict__ agg, int N) {
    int lane = threadIdx.x & 63;
    int node = (blockIdx.x * blockDim.x + threadIdx.x) >> 6;
    if (node >= N) return;
    int beg = off[node], end = off[node + 1];
    float acc = hs[(size_t)node * 64 + lane];  // self loop
    int j = beg;
    for (; j + 4 <= end; j += 4) {
        int s0 = esorted[j], s1 = esorted[j + 1], s2 = esorted[j + 2], s3 = esorted[j + 3];
        float v0 = hs[(size_t)s0 * 64 + lane];
        float v1 = hs[(size_t)s1 * 64 + lane];
        float v2 = hs[(size_t)s2 * 64 + lane];
        float v3 = hs[(size_t)s3 * 64 + lane];
        acc += (v0 + v1) + (v2 + v3);
    }
    for (; j < end; ++j) acc += hs[(size_t)esorted[j] * 64 + lane];
    agg[(size_t)node * 64 + lane] = acc * dinv[node];
}

// ---------- epilogue ----------

__global__ void k_out(const int* __restrict__ idx, const float* __restrict__ agg,
                      const float* __restrict__ b1, const float* __restrict__ Wm,
                      const float* __restrict__ bm, float* __restrict__ out, int NSEL) {
    int lane = threadIdx.x & 63;
    int wv = (blockIdx.x * blockDim.x + threadIdx.x) >> 6;
    if (wv >= NSEL) return;
    int node = idx[wv];
    float hs = lrelu(agg[(size_t)node * 64 + lane] + b1[lane]);
    out[(size_t)wv * 64 + lane] = hs;
#pragma unroll
    for (int o = 0; o < 5; ++o) {
        float p = hs * Wm[lane * 5 + o];
#pragma unroll
        for (int offs = 32; offs > 0; offs >>= 1) p += __shfl_down(p, offs);
        if (lane == 0)
            out[(size_t)NSEL * 64 + (size_t)wv * 5 + o] =
                1.0f / (1.0f + expf(-(p + bm[o])));
    }
}

extern "C" void kernel_launch(void* const* d_in, const int* in_sizes, int n_in,
                              void* d_out, int out_size, void* d_ws, size_t ws_size,
                              hipStream_t stream) {
    const float* x   = (const float*)d_in[0];
    const int*   ei  = (const int*)d_in[1];
    const int*   idx = (const int*)d_in[2];
    const float* W0  = (const float*)d_in[3];
    const float* b0  = (const float*)d_in[4];
    const float* W1  = (const float*)d_in[5];
    const float* b1  = (const float*)d_in[6];
    const float* Wm  = (const float*)d_in[7];
    const float* bm  = (const float*)d_in[8];

    int N    = in_sizes[0] / 128;
    int E    = in_sizes[1] / 2;
    int NSEL = in_sizes[2];
    const int* src = ei;
    const int* dst = ei + E;

    // workspace layout (all 4-byte elems, 1024-elem aligned chunks)
    char* w = (char*)d_ws;
    size_t Na = ((size_t)N + 1023) & ~(size_t)1023;
    size_t Ea = ((size_t)E + 1023) & ~(size_t)1023;
    float* dinv    = (float*)w;                 w += Na * 4;
    int*   cnt     = (int*)w;                   w += Na * 4;
    int*   off     = (int*)w;                   w += (Na + 1024) * 4;
    int*   bsum    = (int*)w;                   w += 1024 * 4;
    int*   esorted = (int*)w;                   w += Ea * 4;
    float* buf1    = (float*)w;                 w += (size_t)N * 64 * 4;  // h_s
    float* buf2    = (float*)w;                                          // agg

    int nb = (N + 1023) / 1024;

    // CSR build + dinv
    hipMemsetAsync(cnt, 0, (size_t)N * sizeof(int), stream);
    k_hist<<<(E + 255) / 256, 256, 0, stream>>>(dst, E, cnt);
    k_dinv<<<(N + 255) / 256, 256, 0, stream>>>(cnt, dinv, N);
    k_blocksum<<<nb, 256, 0, stream>>>(cnt, N, bsum);
    k_scan_bsum<<<1, 64, 0, stream>>>(bsum, nb, off + N);
    k_scan_block<<<nb, 256, 0, stream>>>(cnt, bsum, off, N);
    hipMemsetAsync(cnt, 0, (size_t)N * sizeof(int), stream);
    k_scatter<<<(E + 255) / 256, 256, 0, stream>>>(src, dst, off, cnt, esorted, E);

    int gemm_blocks = (N + 31) / 32;  // 4 waves/block * 8 rows/wave
    int agg_blocks  = (N + 3) / 4;    // 4 waves/block, 1 node/wave

    k_gemm1<<<gemm_blocks, 256, 0, stream>>>(x, W0, dinv, buf1, N);
    k_agg<<<agg_blocks, 256, 0, stream>>>(off, esorted, dinv, buf1, buf2, N);
    k_gemm2<<<gemm_blocks, 256, 0, stream>>>(buf2, b0, W1, dinv, buf1, N);
    k_agg<<<agg_blocks, 256, 0, stream>>>(off, esorted, dinv, buf1, buf2, N);
    k_out<<<(NSEL + 3) / 4, 256, 0, stream>>>(idx, buf2, b1, Wm, bm, (float*)d_out, NSEL);
}